// Round 15
// baseline (144.613 us; speedup 1.0000x reference)
//
#include <hip/hip_runtime.h>

#define NODES 512
#define WORDS 16          // 512 bits / 32
#define NBATCH 32
#define SENTINEL 11       // MAX_DISTANCE + 1
#define NEMB 12           // MAX_DISTANCE + 2
#define NOUT 8
#define G 8               // sources per block
#define NGRP (NODES / G)  // 64 groups per batch

typedef float nf4 __attribute__((ext_vector_type(4)));   // nontemporal-safe f4

// ---------------------------------------------------------------------------
// K1: pack adjacency bits, one u32 word (32 elements, 8x float4) per thread.
// ---------------------------------------------------------------------------
__global__ void __launch_bounds__(256)
pack_bits(const float* __restrict__ A, const int* __restrict__ mask,
          unsigned int* __restrict__ bitA) {
    const int tid = blockIdx.x * 256 + threadIdx.x;   // 262144 words total
    const int t = threadIdx.x;
    const int w = tid & 15;
    const int i = (tid >> 4) & 511;
    const int b = tid >> 13;                          // constant per block

    __shared__ unsigned int s_mw[WORDS];
    {
        bool m0 = mask[b * NODES + t] != 0;
        bool m1 = mask[b * NODES + 256 + t] != 0;
        unsigned long long b0 = __ballot(m0);
        unsigned long long b1 = __ballot(m1);
        if ((t & 63) == 0) {
            int wv = t >> 6;
            s_mw[2 * wv]         = (unsigned int)b0;
            s_mw[2 * wv + 1]     = (unsigned int)(b0 >> 32);
            s_mw[8 + 2 * wv]     = (unsigned int)b1;
            s_mw[8 + 2 * wv + 1] = (unsigned int)(b1 >> 32);
        }
    }

    const float4* p = (const float4*)(A + (size_t)tid * 32);
    unsigned int bits = 0;
#pragma unroll
    for (int q = 0; q < 8; ++q) {
        float4 v = p[q];
        bits |= (v.x > 0.5f ? 1u : 0u) << (4 * q);
        bits |= (v.y > 0.5f ? 1u : 0u) << (4 * q + 1);
        bits |= (v.z > 0.5f ? 1u : 0u) << (4 * q + 2);
        bits |= (v.w > 0.5f ? 1u : 0u) << (4 * q + 3);
    }
    __syncthreads();
    bool rv = (s_mw[i >> 5] >> (i & 31)) & 1u;
    bitA[tid] = rv ? (bits & s_mw[w]) : 0u;
}

// ---------------------------------------------------------------------------
// K2: symmetrize: adj[b,i,w] |= transpose bits (1 MB, L2-resident).
// ---------------------------------------------------------------------------
__global__ void __launch_bounds__(256)
symmetrize(const unsigned int* __restrict__ bitA, unsigned int* __restrict__ adjb) {
    int tid = blockIdx.x * 256 + threadIdx.x;   // total B*N*WORDS = 262144
    int w = tid & 15;
    int i = (tid >> 4) & 511;
    int b = tid >> 13;
    const unsigned int* base = bitA + (size_t)b * NODES * WORDS;
    unsigned int word = base[i * WORDS + w];
    unsigned int t = 0;
    int iw = i >> 5, ib = i & 31;
#pragma unroll
    for (int k = 0; k < 32; ++k) {
        t |= ((base[(32 * w + k) * WORDS + iw] >> ib) & 1u) << k;
    }
    adjb[tid] = word | t;
}

// ---------------------------------------------------------------------------
// K3 (HOT): direct d<=2 + fused store, G=8 sources/block, 256 threads.
// Round-15 change: REGISTER-ONLY store stream. In the hot path d is in
// {0,1,2,11} by construction, so the emb table is 8 f4 in registers
// (v_cndmask select), and each thread stores its OWN two columns straight
// from its packed-dist registers. Zero LDS reads, zero barriers between
// compute and stores — tests the theory that the chained LDS reads per
// store were capping the stream at ~4.5 TB/s (fill does 6.9 with none).
// ---------------------------------------------------------------------------
__global__ void __launch_bounds__(256, 4)
dist2_store(const unsigned int* __restrict__ adjb, const int* __restrict__ mask,
            const float* __restrict__ emb, float4* __restrict__ out4,
            int* __restrict__ flags) {
    const int i0 = blockIdx.x * G;
    const int b = blockIdx.y;
    const int t = threadIdx.x;
    const int cA = t, cB = t + 256;

    __shared__ unsigned int s_rowi[G][WORDS];   // 512 B source rows
    __shared__ unsigned int s_red[4];           // per-wave need-reduction
    __shared__ __align__(16) float s_emb[NEMB * NOUT];

    if (t < NEMB * NOUT) s_emb[t] = emb[t];

    const unsigned int* Ab = adjb + (size_t)b * NODES * WORDS;
    if (t < G * 4) {                            // 32 threads: 8 rows x 16B
        int s = t >> 2, q = t & 3;
        ((uint4*)s_rowi[s])[q] = ((const uint4*)(Ab + (size_t)(i0 + s) * WORDS))[q];
    }

    // Both columns' rows loaded upfront into named regs, held live (r12 fix).
    const uint4* rpA = (const uint4*)(Ab + (size_t)cA * WORDS);
    const uint4* rpB = (const uint4*)(Ab + (size_t)cB * WORDS);
    uint4 a0 = rpA[0], a1 = rpA[1], a2 = rpA[2], a3 = rpA[3];
    uint4 b0 = rpB[0], b1 = rpB[1], b2 = rpB[2], b3 = rpB[3];

    unsigned int vsmask = 0;
#pragma unroll
    for (int s = 0; s < G; ++s)
        vsmask |= (mask[b * NODES + i0 + s] != 0) ? (1u << s) : 0u;
    const bool validA = (mask[b * NODES + cA] != 0);
    const bool validB = (mask[b * NODES + cB] != 0);

    __syncthreads();   // s_rowi, s_emb visible

    unsigned int dwA0 = 0, dwA1 = 0, dwB0 = 0, dwB1 = 0;
    unsigned int has11 = 0, has2 = 0;           // per-source bits (this thread)
#pragma unroll
    for (int s = 0; s < G; ++s) {
        const uint4* R = (const uint4*)s_rowi[s];   // broadcast reads
        uint4 R0 = R[0], R1 = R[1], R2 = R[2], R3 = R[3];
        unsigned int hitA =
            (a0.x & R0.x) | (a0.y & R0.y) | (a0.z & R0.z) | (a0.w & R0.w) |
            (a1.x & R1.x) | (a1.y & R1.y) | (a1.z & R1.z) | (a1.w & R1.w) |
            (a2.x & R2.x) | (a2.y & R2.y) | (a2.z & R2.z) | (a2.w & R2.w) |
            (a3.x & R3.x) | (a3.y & R3.y) | (a3.z & R3.z) | (a3.w & R3.w);
        unsigned int hitB =
            (b0.x & R0.x) | (b0.y & R0.y) | (b0.z & R0.z) | (b0.w & R0.w) |
            (b1.x & R1.x) | (b1.y & R1.y) | (b1.z & R1.z) | (b1.w & R1.w) |
            (b2.x & R2.x) | (b2.y & R2.y) | (b2.z & R2.z) | (b2.w & R2.w) |
            (b3.x & R3.x) | (b3.y & R3.y) | (b3.z & R3.z) | (b3.w & R3.w);
        unsigned int bit1A = (s_rowi[s][cA >> 5] >> (cA & 31)) & 1u;
        unsigned int bit1B = (s_rowi[s][cB >> 5] >> (cB & 31)) & 1u;
        unsigned int dA = (cA == i0 + s && ((vsmask >> s) & 1u)) ? 0u
                          : (bit1A ? 1u : (hitA ? 2u : (unsigned)SENTINEL));
        unsigned int dB = (cB == i0 + s && ((vsmask >> s) & 1u)) ? 0u
                          : (bit1B ? 1u : (hitB ? 2u : (unsigned)SENTINEL));
        if (dA == 2u || dB == 2u) has2 |= 1u << s;
        if ((dA == (unsigned)SENTINEL && validA) ||
            (dB == (unsigned)SENTINEL && validB)) has11 |= 1u << s;
        if (s < 4) { dwA0 |= dA << (8 * s);       dwB0 |= dB << (8 * s); }
        else       { dwA1 |= dA << (8 * (s - 4)); dwB1 |= dB << (8 * (s - 4)); }
    }

    // Register emb table: rows 0,1,2,SENTINEL x {lo,hi} (broadcast LDS reads).
    const nf4* e4 = (const nf4*)s_emb;
    nf4 e0l = e4[0],  e0h = e4[1];
    nf4 e1l = e4[2],  e1h = e4[3];
    nf4 e2l = e4[4],  e2h = e4[5];
    nf4 eSl = e4[2 * SENTINEL], eSh = e4[2 * SENTINEL + 1];

    // Pure-register store stream: thread t stores its own columns cA, cB.
    nf4* o4 = (nf4*)out4;
    size_t base0 = ((size_t)b * NODES + i0) * (NODES * NOUT / 4); // 1024 f4/row
#pragma unroll
    for (int s = 0; s < G; ++s) {
        unsigned int dA = ((s < 4 ? dwA0 >> (8 * s) : dwA1 >> (8 * (s - 4))) & 0xffu);
        unsigned int dB = ((s < 4 ? dwB0 >> (8 * s) : dwB1 >> (8 * (s - 4))) & 0xffu);
        nf4 lA = dA == 0u ? e0l : dA == 1u ? e1l : dA == 2u ? e2l : eSl;
        nf4 hA = dA == 0u ? e0h : dA == 1u ? e1h : dA == 2u ? e2h : eSh;
        nf4 lB = dB == 0u ? e0l : dB == 1u ? e1l : dB == 2u ? e2l : eSl;
        nf4 hB = dB == 0u ? e0h : dB == 1u ? e1h : dB == 2u ? e2h : eSh;
        size_t rowb = base0 + (size_t)s * 1024;
        __builtin_nontemporal_store(lA, &o4[rowb + 2 * cA]);
        __builtin_nontemporal_store(hA, &o4[rowb + 2 * cA + 1]);
        __builtin_nontemporal_store(lB, &o4[rowb + 2 * cB]);
        __builtin_nontemporal_store(hB, &o4[rowb + 2 * cB + 1]);
    }

    // need-fallback consensus (after stores; doesn't gate the stream).
    unsigned int comb = has11 | (has2 << 8);
#pragma unroll
    for (int off = 1; off < 64; off <<= 1) comb |= __shfl_xor(comb, off);
    if ((t & 63) == 0) s_red[t >> 6] = comb;
    __syncthreads();
    unsigned int allc = s_red[0] | s_red[1] | s_red[2] | s_red[3];
    if (t == 0)
        flags[b * NGRP + blockIdx.x] =
            ((allc & (allc >> 8) & vsmask & 0xffu) != 0u) ? 1 : 0;
}

// ---------------------------------------------------------------------------
// K4 (COLD): full general BFS, runs ONLY for flagged groups (never on dense
// inputs). Overwrites the group's 8 output rows. Unchanged from r14 (passed).
// ---------------------------------------------------------------------------
__global__ void __launch_bounds__(256, 4)
bfs_fallback(const unsigned int* __restrict__ adjb, const int* __restrict__ mask,
             const float* __restrict__ emb, float4* __restrict__ out4,
             const int* __restrict__ flags) {
    if (flags[blockIdx.y * NGRP + blockIdx.x] == 0) return;

    const int i0 = blockIdx.x * G;
    const int b = blockIdx.y;
    const int t = threadIdx.x;
    const int cA = t, cB = t + 256;

    __shared__ unsigned int s_rowi[G][WORDS];
    __shared__ unsigned int s_f[2][G][WORDS];
    __shared__ unsigned int s_state[2][4];
    __shared__ unsigned int s_dw0[NODES];
    __shared__ unsigned int s_dw1[NODES];
    __shared__ __align__(16) float s_emb[NEMB * NOUT];

    if (t < NEMB * NOUT) s_emb[t] = emb[t];

    const unsigned int* Ab = adjb + (size_t)b * NODES * WORDS;
    if (t < G * 4) {
        int s = t >> 2, q = t & 3;
        ((uint4*)s_rowi[s])[q] = ((const uint4*)(Ab + (size_t)(i0 + s) * WORDS))[q];
    }

    bool vs[G];
#pragma unroll
    for (int s = 0; s < G; ++s) vs[s] = (mask[b * NODES + i0 + s] != 0);
    const bool validA = (mask[b * NODES + cA] != 0);
    const bool validB = (mask[b * NODES + cB] != 0);

    const uint4* rA = (const uint4*)(Ab + (size_t)cA * WORDS);
    const uint4* rB = (const uint4*)(Ab + (size_t)cB * WORDS);

    __syncthreads();

    unsigned int dwA0 = 0, dwA1 = 0, dwB0 = 0, dwB1 = 0;
    {
        uint4 r0 = rA[0], r1 = rA[1], r2 = rA[2], r3 = rA[3];
#pragma unroll
        for (int s = 0; s < G; ++s) {
            const uint4* R = (const uint4*)s_rowi[s];
            uint4 R0 = R[0], R1 = R[1], R2 = R[2], R3 = R[3];
            unsigned int hit =
                (r0.x & R0.x) | (r0.y & R0.y) | (r0.z & R0.z) | (r0.w & R0.w) |
                (r1.x & R1.x) | (r1.y & R1.y) | (r1.z & R1.z) | (r1.w & R1.w) |
                (r2.x & R2.x) | (r2.y & R2.y) | (r2.z & R2.z) | (r2.w & R2.w) |
                (r3.x & R3.x) | (r3.y & R3.y) | (r3.z & R3.z) | (r3.w & R3.w);
            unsigned int bit1 = (s_rowi[s][cA >> 5] >> (cA & 31)) & 1u;
            unsigned int d = (cA == i0 + s && vs[s]) ? 0u
                             : (bit1 ? 1u : (hit ? 2u : (unsigned)SENTINEL));
            if (s < 4) dwA0 |= d << (8 * s); else dwA1 |= d << (8 * (s - 4));
        }
    }
    {
        uint4 r0 = rB[0], r1 = rB[1], r2 = rB[2], r3 = rB[3];
#pragma unroll
        for (int s = 0; s < G; ++s) {
            const uint4* R = (const uint4*)s_rowi[s];
            uint4 R0 = R[0], R1 = R[1], R2 = R[2], R3 = R[3];
            unsigned int hit =
                (r0.x & R0.x) | (r0.y & R0.y) | (r0.z & R0.z) | (r0.w & R0.w) |
                (r1.x & R1.x) | (r1.y & R1.y) | (r1.z & R1.z) | (r1.w & R1.w) |
                (r2.x & R2.x) | (r2.y & R2.y) | (r2.z & R2.z) | (r2.w & R2.w) |
                (r3.x & R3.x) | (r3.y & R3.y) | (r3.z & R3.z) | (r3.w & R3.w);
            unsigned int bit1 = (s_rowi[s][cB >> 5] >> (cB & 31)) & 1u;
            unsigned int d = (cB == i0 + s && vs[s]) ? 0u
                             : (bit1 ? 1u : (hit ? 2u : (unsigned)SENTINEL));
            if (s < 4) dwB0 |= d << (8 * s); else dwB1 |= d << (8 * (s - 4));
        }
    }

    // seed d==2 frontier
    {
        unsigned long long anyAcc = 0;
#pragma unroll
        for (int s = 0; s < G; ++s) {
            unsigned int dA = ((s < 4 ? dwA0 >> (8 * s) : dwA1 >> (8 * (s - 4))) & 0xffu);
            unsigned int dB = ((s < 4 ? dwB0 >> (8 * s) : dwB1 >> (8 * (s - 4))) & 0xffu);
            unsigned long long fA = __ballot(dA == 2u);
            unsigned long long fB = __ballot(dB == 2u);
            anyAcc |= fA | fB;
            if ((t & 63) == 0) {
                int wv = t >> 6;
                s_f[0][s][2 * wv]         = (unsigned int)fA;
                s_f[0][s][2 * wv + 1]     = (unsigned int)(fA >> 32);
                s_f[0][s][8 + 2 * wv]     = (unsigned int)fB;
                s_f[0][s][8 + 2 * wv + 1] = (unsigned int)(fB >> 32);
            }
        }
        if ((t & 63) == 0) s_state[0][t >> 6] = (anyAcc != 0ull) ? 1u : 0u;
    }
    __syncthreads();
    unsigned int anyw = s_state[0][0] | s_state[0][1] | s_state[0][2] | s_state[0][3];

    if (anyw & 1u) {
        unsigned int reachA = 0, reachB = 0;
#pragma unroll
        for (int s = 0; s < G; ++s) {
            unsigned int dA = ((s < 4 ? dwA0 >> (8 * s) : dwA1 >> (8 * (s - 4))) & 0xffu);
            unsigned int dB = ((s < 4 ? dwB0 >> (8 * s) : dwB1 >> (8 * (s - 4))) & 0xffu);
            if (dA != (unsigned)SENTINEL) reachA |= 1u << s;
            if (dB != (unsigned)SENTINEL) reachB |= 1u << s;
        }
        int p = 0;
        for (int tt = 3; tt <= 10; ++tt) {
            uint4 a0 = rA[0], a1 = rA[1], a2 = rA[2], a3 = rA[3];
            uint4 b0 = rB[0], b1 = rB[1], b2 = rB[2], b3 = rB[3];
            unsigned int newA = 0, newB = 0;
#pragma unroll
            for (int s = 0; s < G; ++s) {
                const uint4* F = (const uint4*)s_f[p][s];
                uint4 f0 = F[0], f1 = F[1], f2 = F[2], f3 = F[3];
                unsigned int hA =
                    (a0.x & f0.x) | (a0.y & f0.y) | (a0.z & f0.z) | (a0.w & f0.w) |
                    (a1.x & f1.x) | (a1.y & f1.y) | (a1.z & f1.z) | (a1.w & f1.w) |
                    (a2.x & f2.x) | (a2.y & f2.y) | (a2.z & f2.z) | (a2.w & f2.w) |
                    (a3.x & f3.x) | (a3.y & f3.y) | (a3.z & f3.z) | (a3.w & f3.w);
                unsigned int hB =
                    (b0.x & f0.x) | (b0.y & f0.y) | (b0.z & f0.z) | (b0.w & f0.w) |
                    (b1.x & f1.x) | (b1.y & f1.y) | (b1.z & f1.z) | (b1.w & f1.w) |
                    (b2.x & f2.x) | (b2.y & f2.y) | (b2.z & f2.z) | (b2.w & f2.w) |
                    (b3.x & f3.x) | (b3.y & f3.y) | (b3.z & f3.z) | (b3.w & f3.w);
                if (hA && !((reachA >> s) & 1u)) newA |= 1u << s;
                if (hB && !((reachB >> s) & 1u)) newB |= 1u << s;
            }
            unsigned long long anyAcc = 0;
#pragma unroll
            for (int s = 0; s < G; ++s) {
                unsigned long long nA = __ballot((newA >> s) & 1u);
                unsigned long long nB = __ballot((newB >> s) & 1u);
                anyAcc |= nA | nB;
                if ((t & 63) == 0) {
                    int wv = t >> 6;
                    s_f[p ^ 1][s][2 * wv]         = (unsigned int)nA;
                    s_f[p ^ 1][s][2 * wv + 1]     = (unsigned int)(nA >> 32);
                    s_f[p ^ 1][s][8 + 2 * wv]     = (unsigned int)nB;
                    s_f[p ^ 1][s][8 + 2 * wv + 1] = (unsigned int)(nB >> 32);
                }
            }
            bool dn = (!validA || ((reachA | newA) == 0xffu)) &&
                      (!validB || ((reachB | newB) == 0xffu));
            unsigned long long bD = __ballot(dn);
            if ((t & 63) == 0)
                s_state[p ^ 1][t >> 6] = ((anyAcc != 0ull) ? 1u : 0u) |
                                         ((bD == ~0ull) ? 2u : 0u);
#pragma unroll
            for (int s = 0; s < G; ++s) {
                if ((newA >> s) & 1u) {
                    if (s < 4) dwA0 = (dwA0 & ~(0xffu << (8 * s))) | ((unsigned)tt << (8 * s));
                    else       dwA1 = (dwA1 & ~(0xffu << (8 * (s - 4)))) | ((unsigned)tt << (8 * (s - 4)));
                }
                if ((newB >> s) & 1u) {
                    if (s < 4) dwB0 = (dwB0 & ~(0xffu << (8 * s))) | ((unsigned)tt << (8 * s));
                    else       dwB1 = (dwB1 & ~(0xffu << (8 * (s - 4)))) | ((unsigned)tt << (8 * (s - 4)));
                }
            }
            reachA |= newA; reachB |= newB;
            __syncthreads();
            p ^= 1;
            unsigned int aw = 0, dw = 2;
#pragma unroll
            for (int wv = 0; wv < 4; ++wv) {
                unsigned int st = s_state[p][wv];
                aw |= st; dw &= st;
            }
            if (!(aw & 1u) || (dw & 2u)) break;
        }
    }

    s_dw0[cA] = dwA0; s_dw1[cA] = dwA1;
    s_dw0[cB] = dwB0; s_dw1[cB] = dwB1;
    __syncthreads();

    const float4* e4 = (const float4*)s_emb;
    size_t base0 = ((size_t)b * NODES + i0) * (NODES * NOUT / 4);
#pragma unroll
    for (int s = 0; s < G; ++s) {
#pragma unroll
        for (int q = 0; q < 4; ++q) {
            int k = q * 256 + t;
            unsigned int wd = (s < 4) ? s_dw0[k >> 1] : s_dw1[k >> 1];
            int d = (int)((wd >> (8 * (s & 3))) & 0xffu);
            out4[base0 + (size_t)s * 1024 + k] = e4[2 * d + (k & 1)];
        }
    }
}

// ---------------------------------------------------------------------------
extern "C" void kernel_launch(void* const* d_in, const int* in_sizes, int n_in,
                              void* d_out, int out_size, void* d_ws, size_t ws_size,
                              hipStream_t stream) {
    const float* adjacency = (const float*)d_in[0];
    const int* node_mask = (const int*)d_in[1];   // bool -> int32 on upload
    const float* emb = (const float*)d_in[2];
    float4* out4 = (float4*)d_out;

    unsigned int* bitA = (unsigned int*)d_ws;                       // 1 MB
    unsigned int* adjb = bitA + (size_t)NBATCH * NODES * WORDS;     // 1 MB
    int* flags = (int*)(adjb + (size_t)NBATCH * NODES * WORDS);     // 8 KB

    // K1: 262144 words -> 1024 blocks
    pack_bits<<<1024, 256, 0, stream>>>(adjacency, node_mask, bitA);
    // K2: 262144 words -> 1024 blocks
    symmetrize<<<1024, 256, 0, stream>>>(bitA, adjb);
    // K3 hot: 2048 blocks; register-only store stream
    dist2_store<<<dim3(NGRP, NBATCH), 256, 0, stream>>>(adjb, node_mask, emb,
                                                        out4, flags);
    // K4 cold: immediate exit unless flagged
    bfs_fallback<<<dim3(NGRP, NBATCH), 256, 0, stream>>>(adjb, node_mask, emb,
                                                         out4, flags);
}

// Round 16
// 79.066 us; speedup vs baseline: 1.8290x; 1.8290x over previous
//
#include <hip/hip_runtime.h>

#define NODES 512
#define WORDS 16          // 512 bits / 32
#define NBATCH 32
#define SENTINEL 11       // MAX_DISTANCE + 1
#define NEMB 12           // MAX_DISTANCE + 2
#define NOUT 8
#define G 2               // sources per BFS block (G=2 -> 64-VGPR fits)

// ---------------------------------------------------------------------------
// K1: pack adjacency bits, one u32 word (32 elements, 8x float4) per thread.
// node_mask (int32 on upload) ballot-packed into LDS once per block.
// ---------------------------------------------------------------------------
__global__ void __launch_bounds__(256)
pack_bits(const float* __restrict__ A, const int* __restrict__ mask,
          unsigned int* __restrict__ bitA) {
    const int tid = blockIdx.x * 256 + threadIdx.x;   // 262144 words total
    const int t = threadIdx.x;
    const int w = tid & 15;
    const int i = (tid >> 4) & 511;
    const int b = tid >> 13;                          // constant per block

    __shared__ unsigned int s_mw[WORDS];
    {
        bool m0 = mask[b * NODES + t] != 0;
        bool m1 = mask[b * NODES + 256 + t] != 0;
        unsigned long long b0 = __ballot(m0);
        unsigned long long b1 = __ballot(m1);
        if ((t & 63) == 0) {
            int wv = t >> 6;
            s_mw[2 * wv]         = (unsigned int)b0;
            s_mw[2 * wv + 1]     = (unsigned int)(b0 >> 32);
            s_mw[8 + 2 * wv]     = (unsigned int)b1;
            s_mw[8 + 2 * wv + 1] = (unsigned int)(b1 >> 32);
        }
    }

    const float4* p = (const float4*)(A + (size_t)tid * 32);
    unsigned int bits = 0;
#pragma unroll
    for (int q = 0; q < 8; ++q) {
        float4 v = p[q];
        bits |= (v.x > 0.5f ? 1u : 0u) << (4 * q);
        bits |= (v.y > 0.5f ? 1u : 0u) << (4 * q + 1);
        bits |= (v.z > 0.5f ? 1u : 0u) << (4 * q + 2);
        bits |= (v.w > 0.5f ? 1u : 0u) << (4 * q + 3);
    }
    __syncthreads();
    bool rv = (s_mw[i >> 5] >> (i & 31)) & 1u;
    bitA[tid] = rv ? (bits & s_mw[w]) : 0u;
}

// ---------------------------------------------------------------------------
// K2: symmetrize: adj[b,i,w] |= transpose bits (1 MB, L2-resident).
// ---------------------------------------------------------------------------
__global__ void __launch_bounds__(256)
symmetrize(const unsigned int* __restrict__ bitA, unsigned int* __restrict__ adjb) {
    int tid = blockIdx.x * 256 + threadIdx.x;   // total B*N*WORDS = 262144
    int w = tid & 15;
    int i = (tid >> 4) & 511;
    int b = tid >> 13;
    const unsigned int* base = bitA + (size_t)b * NODES * WORDS;
    unsigned int word = base[i * WORDS + w];
    unsigned int t = 0;
    int iw = i >> 5, ib = i & 31;
#pragma unroll
    for (int k = 0; k < 32; ++k) {
        t |= ((base[(32 * w + k) * WORDS + iw] >> ib) & 1u) << k;
    }
    adjb[tid] = word | t;
}

// ---------------------------------------------------------------------------
// K3: fused bitset-BFS + embedding store. Block = (G=2 sources, batch),
// 512 threads; thread j holds symmetric adjacency row j in 16 VGPRs.
// Empirical best across 7 structures (79.2us, r8): G=2 fits the
// (512,8)=64-VGPR cap WITHOUT spills -> 4 blocks/CU; double-buffered
// frontier, one barrier/hop; early exit on empty frontier or saturation;
// LDS-redistributed epilogue = lane-contiguous f4 store instructions
// (r15 proved per-instruction lane contiguity is what matters: stride-2
// own-column stores = half-line L2 RMW, +65us).
// ---------------------------------------------------------------------------
__global__ void __launch_bounds__(512, 8)
bfs_store(const unsigned int* __restrict__ adjb, const int* __restrict__ mask,
          const float* __restrict__ emb, float4* __restrict__ out4) {
    const int i0 = blockIdx.x * G;
    const int b = blockIdx.y;
    const int j = threadIdx.x;

    __shared__ unsigned int s_f[2][G][WORDS];
    __shared__ unsigned int s_state[2][8];   // bit0 anyNew, bit1 allDone
    __shared__ unsigned int s_dist[NODES];   // byte s = dist[source s] of column
    __shared__ __align__(16) float s_emb[NEMB * NOUT];

    if (j < NEMB * NOUT) s_emb[j] = emb[j];

    // adjacency row j (64 B) in VGPRs
    const uint4* rowp = (const uint4*)(adjb + ((size_t)b * NODES + j) * WORDS);
    uint4 ar0 = rowp[0], ar1 = rowp[1], ar2 = rowp[2], ar3 = rowp[3];

    const bool valid_j = (mask[b * NODES + j] != 0);

    if (j < G * WORDS) {
        int s = j >> 4, w = j & 15;
        int i = i0 + s;
        bool v = (mask[b * NODES + i] != 0);
        s_f[0][s][w] = (v && (i >> 5) == w) ? (1u << (i & 31)) : 0u;
    }

    unsigned int dists = 0x0B0Bu;     // SENTINEL in both used bytes
    unsigned int reachm = 0;
#pragma unroll
    for (int s = 0; s < G; ++s) {
        if ((j == i0 + s) && valid_j) {
            dists &= ~(0xffu << (8 * s));   // dist 0
            reachm |= 1u << s;
        }
    }
    __syncthreads();

    int p = 0;
    for (int t = 1; t <= 10; ++t) {
        unsigned int newm = 0;
#pragma unroll
        for (int s = 0; s < G; ++s) {
            const uint4* f4 = (const uint4*)s_f[p][s];
            uint4 f0 = f4[0], f1 = f4[1], f2 = f4[2], f3 = f4[3];
            unsigned int hit =
                (ar0.x & f0.x) | (ar0.y & f0.y) | (ar0.z & f0.z) | (ar0.w & f0.w) |
                (ar1.x & f1.x) | (ar1.y & f1.y) | (ar1.z & f1.z) | (ar1.w & f1.w) |
                (ar2.x & f2.x) | (ar2.y & f2.y) | (ar2.z & f2.z) | (ar2.w & f2.w) |
                (ar3.x & f3.x) | (ar3.y & f3.y) | (ar3.z & f3.z) | (ar3.w & f3.w);
            if (hit && !((reachm >> s) & 1u)) newm |= 1u << s;
        }
        unsigned long long bal0 = __ballot(newm & 1u);
        unsigned long long bal1 = __ballot((newm >> 1) & 1u);
        bool alldone = (((reachm | newm) == 3u) || !valid_j);
        unsigned long long balD = __ballot(alldone);
        if ((j & 63) == 0) {
            int wv = j >> 6;
            s_f[p ^ 1][0][2 * wv]     = (unsigned int)bal0;
            s_f[p ^ 1][0][2 * wv + 1] = (unsigned int)(bal0 >> 32);
            s_f[p ^ 1][1][2 * wv]     = (unsigned int)bal1;
            s_f[p ^ 1][1][2 * wv + 1] = (unsigned int)(bal1 >> 32);
            s_state[p ^ 1][wv] = (((bal0 | bal1) != 0ull) ? 1u : 0u) |
                                 ((balD == ~0ull) ? 2u : 0u);
        }
#pragma unroll
        for (int s = 0; s < G; ++s) {
            if ((newm >> s) & 1u)
                dists = (dists & ~(0xffu << (8 * s))) | ((unsigned int)t << (8 * s));
        }
        reachm |= newm;
        __syncthreads();   // next frontier + state visible; old buffer free
        p ^= 1;
        unsigned int anyw = 0, donew = 2;
#pragma unroll
        for (int wv = 0; wv < 8; ++wv) {
            unsigned int st = s_state[p][wv];
            anyw |= st;
            donew &= st;
        }
        if (!(anyw & 1u) || (donew & 2u)) break;
    }

    // Epilogue: column-major packed dist, conflict-free b32 LDS traffic,
    // then 4 lane-contiguous float4 stores (2 per source row).
    s_dist[j] = dists;
    __syncthreads();   // also orders the s_emb writes from kernel start

    const float4* e4 = (const float4*)s_emb;
    unsigned int dw0 = s_dist[j >> 1];          // column j/2      (k=j)
    unsigned int dw1 = s_dist[256 + (j >> 1)];  // column 256+j/2  (k=512+j)
    const int half = j & 1;
    size_t base0 = ((size_t)b * NODES + i0) * (NODES * NOUT / 4); // 1024 f4/row
#pragma unroll
    for (int s = 0; s < G; ++s) {
        int d0 = (dw0 >> (8 * s)) & 0xff;
        int d1 = (dw1 >> (8 * s)) & 0xff;
        out4[base0 + (size_t)s * 1024 + j]       = e4[2 * d0 + half];
        out4[base0 + (size_t)s * 1024 + 512 + j] = e4[2 * d1 + half];
    }
}

// ---------------------------------------------------------------------------
extern "C" void kernel_launch(void* const* d_in, const int* in_sizes, int n_in,
                              void* d_out, int out_size, void* d_ws, size_t ws_size,
                              hipStream_t stream) {
    const float* adjacency = (const float*)d_in[0];
    const int* node_mask = (const int*)d_in[1];   // bool -> int32 on upload
    const float* emb = (const float*)d_in[2];
    float4* out4 = (float4*)d_out;

    unsigned int* bitA = (unsigned int*)d_ws;                       // 1 MB
    unsigned int* adjb = bitA + (size_t)NBATCH * NODES * WORDS;     // 1 MB

    // K1: 262144 words -> 1024 blocks (each thread packs 32 adjacency elems)
    pack_bits<<<1024, 256, 0, stream>>>(adjacency, node_mask, bitA);
    // K2: 262144 words -> 1024 blocks
    symmetrize<<<1024, 256, 0, stream>>>(bitA, adjb);
    // K3: one block per (2 sources, batch); fused BFS + store
    bfs_store<<<dim3(NODES / G, NBATCH), 512, 0, stream>>>(adjb, node_mask, emb, out4);
}